// Round 14
// baseline (182.945 us; speedup 1.0000x reference)
//
#include <hip/hip_runtime.h>

// SplatAwareFeedForward on MI355X (gfx950).
// Pipeline: route -> grid-stride prep (weight transposes + sorted gather-cast of x) ->
//           expert GEMM1/GEMM2 (m97 128x128, compact tile list, 4 blocks/CU) ->
//           dense GEMM3/GEMM4 (m97 128x128, 4 blocks/CU, XCD swizzle).
// Workspace layout (bytes):
//   xg/gbuf @ 0      : 33,554,432  (sorted x bf16 for G1; later reused as dense g-buffer)
//   w1t   @ 33554432 :  8,388,608  (E*[H][D] bf16, transposed W1)
//   w2t   @ 41943040 :  8,388,608  (E*[D][H] bf16, transposed W2)
//   wg1t  @ 50331648 :  2,097,152  ([D][D] bf16, transposed Wg1)
//   wg2t  @ 52428800 :  2,097,152  ([D][D] bf16, transposed Wg2)
//   hbuf  @ 54525952 :  8,388,608  (B*S*H bf16, expert-sorted hidden)
//   rout  @ 62914560 : 33,554,432  (B*S*D bf16, routed output, natural order)
//   offs  @ 96468992 : 68          (E+1 ints)
//   order @ 96469248 : 16,384      (S ints sorted by expert)
//   tileE @ 96485632 : 576         (expert id per 128-row tile, <=144)
//   tileR @ 96486208 : 576         (sorted-row start per 128-row tile)
//   ntl   @ 96486784 : 4           (tile count)

#define DEV __device__ __forceinline__

typedef float f32x4 __attribute__((ext_vector_type(4)));
typedef short short8 __attribute__((ext_vector_type(8)));

DEV unsigned short f2bf(float f) {
  unsigned u = __float_as_uint(f);
  u += 0x7fffu + ((u >> 16) & 1u);   // round-to-nearest-even
  return (unsigned short)(u >> 16);
}

DEV void gload16(const void* g, void* l) {
  __builtin_amdgcn_global_load_lds(
      (const __attribute__((address_space(1))) unsigned int*)g,
      (__attribute__((address_space(3))) unsigned int*)l, 16, 0, 0);
}

DEV float gelu_exact(float v) {
  return 0.5f * v * (1.0f + erff(v * 0.70710678118654752f));
}

// ---------------- routing: sorted order + 128-row tile list (runs FIRST) ----------------
__global__ __launch_bounds__(256) void route_kernel(
    const int* __restrict__ sid, int S, int* __restrict__ offs, int* __restrict__ order,
    int* __restrict__ tileE, int* __restrict__ tileR, int* __restrict__ ntl) {
  __shared__ int cnt[16], cur[16];
  const int t = threadIdx.x;
  if (t < 16) cnt[t] = 0;
  __syncthreads();
  for (int s = t; s < S; s += 256) atomicAdd(&cnt[sid[s]], 1);
  __syncthreads();
  if (t == 0) {
    int a = 0;
    for (int e = 0; e < 16; e++) { offs[e] = a; cur[e] = a; a += cnt[e]; }
    offs[16] = a;
    int nt = 0;
    for (int e = 0; e < 16; e++) {
      const int rows = 4 * cnt[e];
      for (int r = 0; r < rows; r += 128) {
        tileE[nt] = e; tileR[nt] = 4 * offs[e] + r; nt++;
      }
    }
    ntl[0] = nt;
  }
  __syncthreads();
  for (int s = t; s < S; s += 256) {
    int p = atomicAdd(&cur[sid[s]], 1);
    order[p] = s;
  }
}

// ---------------- grid-stride prep: gather-cast + weight transposes ----------------
// 2048 blocks total (8/CU).
// blocks [0,1024): gather-cast, grid-stride over 2,097,152 8-elem segments (8 iters/thread):
//   item = p*128 + cs;  xg[p][cs*8..+8] = bf16(x[(p&3)*S + order[p>>2]][cs*8..+8]).
// blocks [1024,2048): 2560 transpose tiles, ~2.5 tiles/block (uniform branch per block).
__global__ __launch_bounds__(256) void prep_kernel(
    const float* __restrict__ x, const int* __restrict__ order,
    unsigned short* __restrict__ xg,
    const float* __restrict__ W1, unsigned short* __restrict__ w1t,
    const float* __restrict__ W2, unsigned short* __restrict__ w2t,
    const float* __restrict__ Wg1, unsigned short* __restrict__ wg1t,
    const float* __restrict__ Wg2, unsigned short* __restrict__ wg2t) {
  const int t = threadIdx.x;
  const int bid = (int)blockIdx.x;
  if (bid < 1024) {                       // ---- gather-cast, grid-stride ----
    const int idx0 = bid * 256 + t;       // 0..262143
#pragma unroll
    for (int s = 0; s < 8; s++) {
      const int item = idx0 + s * 262144; // 0..2097151
      const int p = item >> 7;            // sorted row 0..16383
      const int cs = item & 127;          // col segment
      const long srcrow = (long)(p & 3) * 4096 + order[p >> 2];
      const float* src = x + srcrow * 1024 + cs * 8;
      float4 v0 = *(const float4*)(src);
      float4 v1 = *(const float4*)(src + 4);
      uint4 o;
      o.x = (unsigned)f2bf(v0.x) | ((unsigned)f2bf(v0.y) << 16);
      o.y = (unsigned)f2bf(v0.z) | ((unsigned)f2bf(v0.w) << 16);
      o.z = (unsigned)f2bf(v1.x) | ((unsigned)f2bf(v1.y) << 16);
      o.w = (unsigned)f2bf(v1.z) | ((unsigned)f2bf(v1.w) << 16);
      *(uint4*)(xg + (long)p * 1024 + cs * 8) = o;
    }
    return;
  }
  // ---- weight transposes: tiles id = (bid-1024) + k*1024, k<3, id<2560 ----
  __shared__ float tile[64][65];
  const int tb = bid - 1024;
  for (int k = 0; k < 3; k++) {
    int id = tb + k * 1024;
    if (id >= 2560) break;                // uniform per block
    const float* in; unsigned short* out;
    int R, C, r0, c0; long base;
    if (id < 1024) {          // W1: [1024][256] -> [256][1024] per expert
      in = W1; out = w1t; R = 1024; C = 256;
      base = (long)(id >> 6) * 262144;
      r0 = ((id >> 2) & 15) * 64; c0 = (id & 3) * 64;
    } else if (id < 2048) {   // W2: [256][1024] -> [1024][256] per expert
      id -= 1024;
      in = W2; out = w2t; R = 256; C = 1024;
      base = (long)(id >> 6) * 262144;
      r0 = ((id >> 4) & 3) * 64; c0 = (id & 15) * 64;
    } else if (id < 2304) {   // Wg1
      id -= 2048;
      in = Wg1; out = wg1t; R = 1024; C = 1024; base = 0;
      r0 = (id >> 4) * 64; c0 = (id & 15) * 64;
    } else {                  // Wg2
      id -= 2304;
      in = Wg2; out = wg2t; R = 1024; C = 1024; base = 0;
      r0 = (id >> 4) * 64; c0 = (id & 15) * 64;
    }
    const int cc = t & 63, rr = t >> 6;
#pragma unroll
    for (int i = 0; i < 16; i++) {
      int r = rr + i * 4;
      tile[r][cc] = in[base + (long)(r0 + r) * C + (c0 + cc)];
    }
    __syncthreads();
#pragma unroll
    for (int i = 0; i < 16; i++) {
      int c = rr + i * 4;
      out[base + (long)(c0 + c) * R + (r0 + cc)] = f2bf(tile[cc][c]);
    }
    __syncthreads();                      // tile reads done before next iteration
  }
}

// ---------------- expert 128x128x64 GEMM (m97 structure, compact tile list) ----------------
template <bool GELU, bool SCATTER_C>
__global__ __launch_bounds__(256, 4) void gemm_expert(
    const unsigned short* __restrict__ A, const unsigned short* __restrict__ BT,
    const float* __restrict__ bias, unsigned short* __restrict__ Cout,
    int N, int K,
    const int* __restrict__ order, const int* __restrict__ offs,
    const int* __restrict__ tileE, const int* __restrict__ tileR,
    const int* __restrict__ ntl,
    int S, long btStride, int biasStride) {
  const int ti = (int)blockIdx.y;
  if (ti >= ntl[0]) return;
  const int t = (int)threadIdx.x;
  const int lane = t & 63;
  const int w = t >> 6;
  const int wm = w >> 1, wn = w & 1;
  const int tileN = (int)blockIdx.x;

  const int e = tileE[ti];
  const int rowBase = tileR[ti];
  int Me = 4 * offs[e + 1] - rowBase;
  if (Me > 128) Me = 128;
  const unsigned short* bt = BT + (long)e * btStride;
  const float* bs = bias + (long)e * biasStride;

  __shared__ __align__(16) unsigned short lA[128 * 64];
  __shared__ __align__(16) unsigned short lB[128 * 64];

  const unsigned short* aSrc[4];
  const unsigned short* bSrc[4];
  {
    const int q = t & 7;
#pragma unroll
    for (int i = 0; i < 4; i++) {
      const int row = i * 32 + (t >> 3);
      const int koff = ((q * 16) ^ ((row & 7) << 4)) >> 1;
      const int rr = (row < Me) ? row : (Me - 1);
      aSrc[i] = A + (long)(rowBase + rr) * K + koff;
      const int col = tileN * 128 + row;
      bSrc[i] = bt + (long)col * K + koff;
    }
  }

  f32x4 acc[4][4] = {};

  const int KT = K >> 6;
  for (int kt = 0; kt < KT; kt++) {
    __syncthreads();
#pragma unroll
    for (int i = 0; i < 4; i++) {
      gload16(aSrc[i] + (kt << 6), (void*)(lA + i * 2048 + w * 512));
      gload16(bSrc[i] + (kt << 6), (void*)(lB + i * 2048 + w * 512));
    }
    __syncthreads();
#pragma unroll
    for (int kk = 0; kk < 2; kk++) {
      short8 af[4], bfr[4];
      const int kbyte = kk * 64 + (lane >> 4) * 16;
#pragma unroll
      for (int mi = 0; mi < 4; mi++) {
        const int row = wm * 64 + mi * 16 + (lane & 15);
        const int off = row * 128 + (kbyte ^ ((row & 7) << 4));
        af[mi] = *(const short8*)((const char*)lA + off);
      }
#pragma unroll
      for (int ni = 0; ni < 4; ni++) {
        const int row = wn * 64 + ni * 16 + (lane & 15);
        const int off = row * 128 + (kbyte ^ ((row & 7) << 4));
        bfr[ni] = *(const short8*)((const char*)lB + off);
      }
#pragma unroll
      for (int mi = 0; mi < 4; mi++)
#pragma unroll
        for (int ni = 0; ni < 4; ni++)
          acc[mi][ni] = __builtin_amdgcn_mfma_f32_16x16x32_bf16(af[mi], bfr[ni], acc[mi][ni], 0, 0, 0);
    }
  }

  float bcol[4];
#pragma unroll
  for (int ni = 0; ni < 4; ni++)
    bcol[ni] = bs[tileN * 128 + wn * 64 + ni * 16 + (lane & 15)];

#pragma unroll
  for (int mi = 0; mi < 4; mi++) {
#pragma unroll
    for (int j = 0; j < 4; j++) {
      const int lrow = wm * 64 + mi * 16 + ((lane >> 4) * 4) + j;
      if (lrow >= Me) continue;
      const int g = rowBase + lrow;
      long crow;
      if (SCATTER_C) crow = (long)(g & 3) * S + order[g >> 2];   // natural rows
      else crow = g;                                             // sorted rows
#pragma unroll
      for (int ni = 0; ni < 4; ni++) {
        float v = acc[mi][ni][j] + bcol[ni];
        if (GELU) v = gelu_exact(v);
        Cout[crow * (long)N + tileN * 128 + wn * 64 + ni * 16 + (lane & 15)] = f2bf(v);
      }
    }
  }
}

// ---------------- dense 128x128x64 GEMM (m97 structure, 4 blocks/CU, XCD swizzle) ----------------
template <bool GELU, bool OUT_F32>
__global__ __launch_bounds__(256, 4) void gemm_dense128(
    const unsigned short* __restrict__ A, const unsigned short* __restrict__ BT,
    const float* __restrict__ bias, void* __restrict__ Cout,
    int N, int K, int ntiles) {
  const int t = (int)threadIdx.x;
  const int lane = t & 63;
  const int w = t >> 6;
  const int wm = w >> 1, wn = w & 1;

  const int cpx = (int)gridDim.x >> 3;
  const int swz = ((int)blockIdx.x & 7) * cpx + ((int)blockIdx.x >> 3);
  const int mtile = swz / ntiles, ntile = swz % ntiles;

  __shared__ __align__(16) unsigned short lA[128 * 64];
  __shared__ __align__(16) unsigned short lB[128 * 64];

  const unsigned short* aSrc[4];
  const unsigned short* bSrc[4];
  {
    const int q = t & 7;
#pragma unroll
    for (int i = 0; i < 4; i++) {
      const int row = i * 32 + (t >> 3);
      const int koff = ((q * 16) ^ ((row & 7) << 4)) >> 1;
      aSrc[i] = A + (long)(mtile * 128 + row) * K + koff;
      bSrc[i] = BT + (long)(ntile * 128 + row) * K + koff;
    }
  }

  f32x4 acc[4][4] = {};

  const int KT = K >> 6;
  for (int kt = 0; kt < KT; kt++) {
    __syncthreads();
#pragma unroll
    for (int i = 0; i < 4; i++) {
      gload16(aSrc[i] + (kt << 6), (void*)(lA + i * 2048 + w * 512));
      gload16(bSrc[i] + (kt << 6), (void*)(lB + i * 2048 + w * 512));
    }
    __syncthreads();
#pragma unroll
    for (int kk = 0; kk < 2; kk++) {
      short8 af[4], bfr[4];
      const int kbyte = kk * 64 + (lane >> 4) * 16;
#pragma unroll
      for (int mi = 0; mi < 4; mi++) {
        const int row = wm * 64 + mi * 16 + (lane & 15);
        const int off = row * 128 + (kbyte ^ ((row & 7) << 4));
        af[mi] = *(const short8*)((const char*)lA + off);
      }
#pragma unroll
      for (int ni = 0; ni < 4; ni++) {
        const int row = wn * 64 + ni * 16 + (lane & 15);
        const int off = row * 128 + (kbyte ^ ((row & 7) << 4));
        bfr[ni] = *(const short8*)((const char*)lB + off);
      }
#pragma unroll
      for (int mi = 0; mi < 4; mi++)
#pragma unroll
        for (int ni = 0; ni < 4; ni++)
          acc[mi][ni] = __builtin_amdgcn_mfma_f32_16x16x32_bf16(af[mi], bfr[ni], acc[mi][ni], 0, 0, 0);
    }
  }

  float bcol[4];
#pragma unroll
  for (int ni = 0; ni < 4; ni++)
    bcol[ni] = bias[ntile * 128 + wn * 64 + ni * 16 + (lane & 15)];

#pragma unroll
  for (int mi = 0; mi < 4; mi++) {
#pragma unroll
    for (int j = 0; j < 4; j++) {
      const long crow = mtile * 128 + wm * 64 + mi * 16 + ((lane >> 4) * 4) + j;
#pragma unroll
      for (int ni = 0; ni < 4; ni++) {
        float v = acc[mi][ni][j] + bcol[ni];
        if (GELU) v = gelu_exact(v);
        const long cidx = crow * (long)N + ntile * 128 + wn * 64 + ni * 16 + (lane & 15);
        if (OUT_F32) ((float*)Cout)[cidx] = v;
        else ((unsigned short*)Cout)[cidx] = f2bf(v);
      }
    }
  }
}

extern "C" void kernel_launch(void* const* d_in, const int* in_sizes, int n_in,
                              void* d_out, int out_size, void* d_ws, size_t ws_size,
                              hipStream_t stream) {
  const float* x   = (const float*)d_in[0];
  const int*   sid = (const int*)d_in[1];
  const float* W1  = (const float*)d_in[2];
  const float* b1  = (const float*)d_in[3];
  const float* W2  = (const float*)d_in[4];
  const float* b2  = (const float*)d_in[5];
  const float* Wg1 = (const float*)d_in[6];
  const float* bg1 = (const float*)d_in[7];
  const float* Wg2 = (const float*)d_in[8];
  const float* bg2 = (const float*)d_in[9];
  (void)in_sizes; (void)n_in; (void)out_size; (void)ws_size;

  constexpr int D = 1024, H = 256, S = 4096, B = 4;
  constexpr long NT = (long)B * S;  // 16384 token rows

  char* ws = (char*)d_ws;
  unsigned short* xg   = (unsigned short*)(ws);          // sorted x bf16; reused as gbuf
  unsigned short* w1t  = (unsigned short*)(ws + 33554432);
  unsigned short* w2t  = (unsigned short*)(ws + 41943040);
  unsigned short* wg1t = (unsigned short*)(ws + 50331648);
  unsigned short* wg2t = (unsigned short*)(ws + 52428800);
  unsigned short* hbuf = (unsigned short*)(ws + 54525952);
  unsigned short* rout = (unsigned short*)(ws + 62914560);
  int* offs  = (int*)(ws + 96468992);
  int* order = (int*)(ws + 96469248);
  int* tileE = (int*)(ws + 96485632);
  int* tileR = (int*)(ws + 96486208);
  int* ntl   = (int*)(ws + 96486784);

  route_kernel<<<1, 256, 0, stream>>>(sid, S, offs, order, tileE, tileR, ntl);
  prep_kernel<<<dim3(2048), 256, 0, stream>>>(
      x, order, xg, W1, w1t, W2, w2t, Wg1, wg1t, Wg2, wg2t);

  // GEMM1: h = gelu(xg @ W1[e] + b1[e])   [sorted rows in/out]
  gemm_expert<true, false><<<dim3(H / 128, 144), 256, 0, stream>>>(
      xg, w1t, b1, hbuf, H, D, order, offs, tileE, tileR, ntl, S, (long)H * D, H);
  // GEMM2: rout = h @ W2[e] + b2[e]       [sorted in, scatter to natural rows]
  gemm_expert<false, true><<<dim3(D / 128, 144), 256, 0, stream>>>(
      hbuf, w2t, b2, rout, D, H, order, offs, tileE, tileR, ntl, S, (long)D * H, D);
  // GEMM3: g = gelu(rout @ Wg1 + bg1)     [writes xg region (xg no longer needed)]
  gemm_dense128<true, false><<<dim3((unsigned)(NT / 128) * (D / 128)), 256, 0, stream>>>(
      rout, wg1t, bg1, xg, D, D, D / 128);
  // GEMM4: out = g @ Wg2 + bg2            [fp32 to d_out]
  gemm_dense128<false, true><<<dim3((unsigned)(NT / 128) * (D / 128)), 256, 0, stream>>>(
      xg, wg2t, bg2, d_out, D, D, D / 128);
}

// Round 15
// 180.367 us; speedup vs baseline: 1.0143x; 1.0143x over previous
//
#include <hip/hip_runtime.h>

// SplatAwareFeedForward on MI355X (gfx950).
// Pipeline: route -> prep (ILP-forced gather-cast + weight transposes) ->
//           expert GEMM1/GEMM2 (m97 128x128, compact tile list, 4 blocks/CU) ->
//           dense GEMM3/GEMM4 (m97 128x128, 4 blocks/CU, XCD swizzle).
// Workspace layout (bytes):
//   xg/gbuf @ 0      : 33,554,432  (sorted x bf16 for G1; later reused as dense g-buffer)
//   w1t   @ 33554432 :  8,388,608  (E*[H][D] bf16, transposed W1)
//   w2t   @ 41943040 :  8,388,608  (E*[D][H] bf16, transposed W2)
//   wg1t  @ 50331648 :  2,097,152  ([D][D] bf16, transposed Wg1)
//   wg2t  @ 52428800 :  2,097,152  ([D][D] bf16, transposed Wg2)
//   hbuf  @ 54525952 :  8,388,608  (B*S*H bf16, expert-sorted hidden)
//   rout  @ 62914560 : 33,554,432  (B*S*D bf16, routed output, natural order)
//   offs  @ 96468992 : 68          (E+1 ints)
//   order @ 96469248 : 16,384      (S ints sorted by expert)
//   tileE @ 96485632 : 576         (expert id per 128-row tile, <=144)
//   tileR @ 96486208 : 576         (sorted-row start per 128-row tile)
//   ntl   @ 96486784 : 4           (tile count)

#define DEV __device__ __forceinline__

typedef float f32x4 __attribute__((ext_vector_type(4)));
typedef short short8 __attribute__((ext_vector_type(8)));

DEV unsigned short f2bf(float f) {
  unsigned u = __float_as_uint(f);
  u += 0x7fffu + ((u >> 16) & 1u);   // round-to-nearest-even
  return (unsigned short)(u >> 16);
}

DEV void gload16(const void* g, void* l) {
  __builtin_amdgcn_global_load_lds(
      (const __attribute__((address_space(1))) unsigned int*)g,
      (__attribute__((address_space(3))) unsigned int*)l, 16, 0, 0);
}

DEV float gelu_exact(float v) {
  return 0.5f * v * (1.0f + erff(v * 0.70710678118654752f));
}

// ---------------- routing: sorted order + 128-row tile list (runs FIRST) ----------------
__global__ __launch_bounds__(256) void route_kernel(
    const int* __restrict__ sid, int S, int* __restrict__ offs, int* __restrict__ order,
    int* __restrict__ tileE, int* __restrict__ tileR, int* __restrict__ ntl) {
  __shared__ int cnt[16], cur[16];
  const int t = threadIdx.x;
  if (t < 16) cnt[t] = 0;
  __syncthreads();
  for (int s = t; s < S; s += 256) atomicAdd(&cnt[sid[s]], 1);
  __syncthreads();
  if (t == 0) {
    int a = 0;
    for (int e = 0; e < 16; e++) { offs[e] = a; cur[e] = a; a += cnt[e]; }
    offs[16] = a;
    int nt = 0;
    for (int e = 0; e < 16; e++) {
      const int rows = 4 * cnt[e];
      for (int r = 0; r < rows; r += 128) {
        tileE[nt] = e; tileR[nt] = 4 * offs[e] + r; nt++;
      }
    }
    ntl[0] = nt;
  }
  __syncthreads();
  for (int s = t; s < S; s += 256) {
    int p = atomicAdd(&cur[sid[s]], 1);
    order[p] = s;
  }
}

// ---------------- prep: ILP-forced gather-cast + weight transposes ----------------
// 2048 blocks. blocks [0,1024): gather-cast with EXPLICIT ILP — three separated
// full-unroll passes (order loads -> 16 concurrent float4 loads -> stores), register
// arrays force ~90 VGPR so the compiler cannot serialize the loop (r14: VGPR=32 ->
// one load in flight -> 2.3 TB/s). blocks [1024,2048): 2560 transpose tiles.
__global__ __launch_bounds__(256) void prep_kernel(
    const float* __restrict__ x, const int* __restrict__ order,
    unsigned short* __restrict__ xg,
    const float* __restrict__ W1, unsigned short* __restrict__ w1t,
    const float* __restrict__ W2, unsigned short* __restrict__ w2t,
    const float* __restrict__ Wg1, unsigned short* __restrict__ wg1t,
    const float* __restrict__ Wg2, unsigned short* __restrict__ wg2t) {
  const int t = threadIdx.x;
  const int bid = (int)blockIdx.x;
  if (bid < 1024) {                       // ---- gather-cast, explicit ILP ----
    const int idx0 = bid * 256 + t;       // 0..262143; item = idx0 + s*262144
    int ordv[8];
#pragma unroll
    for (int s = 0; s < 8; s++)
      ordv[s] = order[(idx0 + s * 262144) >> 9];     // (item>>7)>>2
    float4 v0[8], v1[8];
#pragma unroll
    for (int s = 0; s < 8; s++) {
      const int item = idx0 + s * 262144;
      const int p = item >> 7;
      const int cs = item & 127;
      const float* src = x + ((long)(p & 3) * 4096 + ordv[s]) * 1024 + cs * 8;
      v0[s] = *(const float4*)(src);
      v1[s] = *(const float4*)(src + 4);
    }
#pragma unroll
    for (int s = 0; s < 8; s++) {
      const int item = idx0 + s * 262144;
      const int p = item >> 7;
      const int cs = item & 127;
      uint4 o;
      o.x = (unsigned)f2bf(v0[s].x) | ((unsigned)f2bf(v0[s].y) << 16);
      o.y = (unsigned)f2bf(v0[s].z) | ((unsigned)f2bf(v0[s].w) << 16);
      o.z = (unsigned)f2bf(v1[s].x) | ((unsigned)f2bf(v1[s].y) << 16);
      o.w = (unsigned)f2bf(v1[s].z) | ((unsigned)f2bf(v1[s].w) << 16);
      *(uint4*)(xg + (long)p * 1024 + cs * 8) = o;
    }
    return;
  }
  // ---- weight transposes: tiles id = (bid-1024) + k*1024, k<3, id<2560 ----
  __shared__ float tile[64][65];
  const int tb = bid - 1024;
  for (int k = 0; k < 3; k++) {
    int id = tb + k * 1024;
    if (id >= 2560) break;                // uniform per block
    const float* in; unsigned short* out;
    int R, C, r0, c0; long base;
    if (id < 1024) {          // W1: [1024][256] -> [256][1024] per expert
      in = W1; out = w1t; R = 1024; C = 256;
      base = (long)(id >> 6) * 262144;
      r0 = ((id >> 2) & 15) * 64; c0 = (id & 3) * 64;
    } else if (id < 2048) {   // W2: [256][1024] -> [1024][256] per expert
      id -= 1024;
      in = W2; out = w2t; R = 256; C = 1024;
      base = (long)(id >> 6) * 262144;
      r0 = ((id >> 4) & 3) * 64; c0 = (id & 15) * 64;
    } else if (id < 2304) {   // Wg1
      id -= 2048;
      in = Wg1; out = wg1t; R = 1024; C = 1024; base = 0;
      r0 = (id >> 4) * 64; c0 = (id & 15) * 64;
    } else {                  // Wg2
      id -= 2304;
      in = Wg2; out = wg2t; R = 1024; C = 1024; base = 0;
      r0 = (id >> 4) * 64; c0 = (id & 15) * 64;
    }
    const int cc = t & 63, rr = t >> 6;
#pragma unroll
    for (int i = 0; i < 16; i++) {
      int r = rr + i * 4;
      tile[r][cc] = in[base + (long)(r0 + r) * C + (c0 + cc)];
    }
    __syncthreads();
#pragma unroll
    for (int i = 0; i < 16; i++) {
      int c = rr + i * 4;
      out[base + (long)(c0 + c) * R + (r0 + cc)] = f2bf(tile[cc][c]);
    }
    __syncthreads();                      // tile reads done before next iteration
  }
}

// ---------------- expert 128x128x64 GEMM (m97 structure, compact tile list) ----------------
template <bool GELU, bool SCATTER_C>
__global__ __launch_bounds__(256, 4) void gemm_expert(
    const unsigned short* __restrict__ A, const unsigned short* __restrict__ BT,
    const float* __restrict__ bias, unsigned short* __restrict__ Cout,
    int N, int K,
    const int* __restrict__ order, const int* __restrict__ offs,
    const int* __restrict__ tileE, const int* __restrict__ tileR,
    const int* __restrict__ ntl,
    int S, long btStride, int biasStride) {
  const int ti = (int)blockIdx.y;
  if (ti >= ntl[0]) return;
  const int t = (int)threadIdx.x;
  const int lane = t & 63;
  const int w = t >> 6;
  const int wm = w >> 1, wn = w & 1;
  const int tileN = (int)blockIdx.x;

  const int e = tileE[ti];
  const int rowBase = tileR[ti];
  int Me = 4 * offs[e + 1] - rowBase;
  if (Me > 128) Me = 128;
  const unsigned short* bt = BT + (long)e * btStride;
  const float* bs = bias + (long)e * biasStride;

  __shared__ __align__(16) unsigned short lA[128 * 64];
  __shared__ __align__(16) unsigned short lB[128 * 64];

  const unsigned short* aSrc[4];
  const unsigned short* bSrc[4];
  {
    const int q = t & 7;
#pragma unroll
    for (int i = 0; i < 4; i++) {
      const int row = i * 32 + (t >> 3);
      const int koff = ((q * 16) ^ ((row & 7) << 4)) >> 1;
      const int rr = (row < Me) ? row : (Me - 1);
      aSrc[i] = A + (long)(rowBase + rr) * K + koff;
      const int col = tileN * 128 + row;
      bSrc[i] = bt + (long)col * K + koff;
    }
  }

  f32x4 acc[4][4] = {};

  const int KT = K >> 6;
  for (int kt = 0; kt < KT; kt++) {
    __syncthreads();
#pragma unroll
    for (int i = 0; i < 4; i++) {
      gload16(aSrc[i] + (kt << 6), (void*)(lA + i * 2048 + w * 512));
      gload16(bSrc[i] + (kt << 6), (void*)(lB + i * 2048 + w * 512));
    }
    __syncthreads();
#pragma unroll
    for (int kk = 0; kk < 2; kk++) {
      short8 af[4], bfr[4];
      const int kbyte = kk * 64 + (lane >> 4) * 16;
#pragma unroll
      for (int mi = 0; mi < 4; mi++) {
        const int row = wm * 64 + mi * 16 + (lane & 15);
        const int off = row * 128 + (kbyte ^ ((row & 7) << 4));
        af[mi] = *(const short8*)((const char*)lA + off);
      }
#pragma unroll
      for (int ni = 0; ni < 4; ni++) {
        const int row = wn * 64 + ni * 16 + (lane & 15);
        const int off = row * 128 + (kbyte ^ ((row & 7) << 4));
        bfr[ni] = *(const short8*)((const char*)lB + off);
      }
#pragma unroll
      for (int mi = 0; mi < 4; mi++)
#pragma unroll
        for (int ni = 0; ni < 4; ni++)
          acc[mi][ni] = __builtin_amdgcn_mfma_f32_16x16x32_bf16(af[mi], bfr[ni], acc[mi][ni], 0, 0, 0);
    }
  }

  float bcol[4];
#pragma unroll
  for (int ni = 0; ni < 4; ni++)
    bcol[ni] = bs[tileN * 128 + wn * 64 + ni * 16 + (lane & 15)];

#pragma unroll
  for (int mi = 0; mi < 4; mi++) {
#pragma unroll
    for (int j = 0; j < 4; j++) {
      const int lrow = wm * 64 + mi * 16 + ((lane >> 4) * 4) + j;
      if (lrow >= Me) continue;
      const int g = rowBase + lrow;
      long crow;
      if (SCATTER_C) crow = (long)(g & 3) * S + order[g >> 2];   // natural rows
      else crow = g;                                             // sorted rows
#pragma unroll
      for (int ni = 0; ni < 4; ni++) {
        float v = acc[mi][ni][j] + bcol[ni];
        if (GELU) v = gelu_exact(v);
        Cout[crow * (long)N + tileN * 128 + wn * 64 + ni * 16 + (lane & 15)] = f2bf(v);
      }
    }
  }
}

// ---------------- dense 128x128x64 GEMM (m97 structure, 4 blocks/CU, XCD swizzle) ----------------
template <bool GELU, bool OUT_F32>
__global__ __launch_bounds__(256, 4) void gemm_dense128(
    const unsigned short* __restrict__ A, const unsigned short* __restrict__ BT,
    const float* __restrict__ bias, void* __restrict__ Cout,
    int N, int K, int ntiles) {
  const int t = (int)threadIdx.x;
  const int lane = t & 63;
  const int w = t >> 6;
  const int wm = w >> 1, wn = w & 1;

  const int cpx = (int)gridDim.x >> 3;
  const int swz = ((int)blockIdx.x & 7) * cpx + ((int)blockIdx.x >> 3);
  const int mtile = swz / ntiles, ntile = swz % ntiles;

  __shared__ __align__(16) unsigned short lA[128 * 64];
  __shared__ __align__(16) unsigned short lB[128 * 64];

  const unsigned short* aSrc[4];
  const unsigned short* bSrc[4];
  {
    const int q = t & 7;
#pragma unroll
    for (int i = 0; i < 4; i++) {
      const int row = i * 32 + (t >> 3);
      const int koff = ((q * 16) ^ ((row & 7) << 4)) >> 1;
      aSrc[i] = A + (long)(mtile * 128 + row) * K + koff;
      bSrc[i] = BT + (long)(ntile * 128 + row) * K + koff;
    }
  }

  f32x4 acc[4][4] = {};

  const int KT = K >> 6;
  for (int kt = 0; kt < KT; kt++) {
    __syncthreads();
#pragma unroll
    for (int i = 0; i < 4; i++) {
      gload16(aSrc[i] + (kt << 6), (void*)(lA + i * 2048 + w * 512));
      gload16(bSrc[i] + (kt << 6), (void*)(lB + i * 2048 + w * 512));
    }
    __syncthreads();
#pragma unroll
    for (int kk = 0; kk < 2; kk++) {
      short8 af[4], bfr[4];
      const int kbyte = kk * 64 + (lane >> 4) * 16;
#pragma unroll
      for (int mi = 0; mi < 4; mi++) {
        const int row = wm * 64 + mi * 16 + (lane & 15);
        const int off = row * 128 + (kbyte ^ ((row & 7) << 4));
        af[mi] = *(const short8*)((const char*)lA + off);
      }
#pragma unroll
      for (int ni = 0; ni < 4; ni++) {
        const int row = wn * 64 + ni * 16 + (lane & 15);
        const int off = row * 128 + (kbyte ^ ((row & 7) << 4));
        bfr[ni] = *(const short8*)((const char*)lB + off);
      }
#pragma unroll
      for (int mi = 0; mi < 4; mi++)
#pragma unroll
        for (int ni = 0; ni < 4; ni++)
          acc[mi][ni] = __builtin_amdgcn_mfma_f32_16x16x32_bf16(af[mi], bfr[ni], acc[mi][ni], 0, 0, 0);
    }
  }

  float bcol[4];
#pragma unroll
  for (int ni = 0; ni < 4; ni++)
    bcol[ni] = bias[ntile * 128 + wn * 64 + ni * 16 + (lane & 15)];

#pragma unroll
  for (int mi = 0; mi < 4; mi++) {
#pragma unroll
    for (int j = 0; j < 4; j++) {
      const long crow = mtile * 128 + wm * 64 + mi * 16 + ((lane >> 4) * 4) + j;
#pragma unroll
      for (int ni = 0; ni < 4; ni++) {
        float v = acc[mi][ni][j] + bcol[ni];
        if (GELU) v = gelu_exact(v);
        const long cidx = crow * (long)N + ntile * 128 + wn * 64 + ni * 16 + (lane & 15);
        if (OUT_F32) ((float*)Cout)[cidx] = v;
        else ((unsigned short*)Cout)[cidx] = f2bf(v);
      }
    }
  }
}

extern "C" void kernel_launch(void* const* d_in, const int* in_sizes, int n_in,
                              void* d_out, int out_size, void* d_ws, size_t ws_size,
                              hipStream_t stream) {
  const float* x   = (const float*)d_in[0];
  const int*   sid = (const int*)d_in[1];
  const float* W1  = (const float*)d_in[2];
  const float* b1  = (const float*)d_in[3];
  const float* W2  = (const float*)d_in[4];
  const float* b2  = (const float*)d_in[5];
  const float* Wg1 = (const float*)d_in[6];
  const float* bg1 = (const float*)d_in[7];
  const float* Wg2 = (const float*)d_in[8];
  const float* bg2 = (const float*)d_in[9];
  (void)in_sizes; (void)n_in; (void)out_size; (void)ws_size;

  constexpr int D = 1024, H = 256, S = 4096, B = 4;
  constexpr long NT = (long)B * S;  // 16384 token rows

  char* ws = (char*)d_ws;
  unsigned short* xg   = (unsigned short*)(ws);          // sorted x bf16; reused as gbuf
  unsigned short* w1t  = (unsigned short*)(ws + 33554432);
  unsigned short* w2t  = (unsigned short*)(ws + 41943040);
  unsigned short* wg1t = (unsigned short*)(ws + 50331648);
  unsigned short* wg2t = (unsigned short*)(ws + 52428800);
  unsigned short* hbuf = (unsigned short*)(ws + 54525952);
  unsigned short* rout = (unsigned short*)(ws + 62914560);
  int* offs  = (int*)(ws + 96468992);
  int* order = (int*)(ws + 96469248);
  int* tileE = (int*)(ws + 96485632);
  int* tileR = (int*)(ws + 96486208);
  int* ntl   = (int*)(ws + 96486784);

  route_kernel<<<1, 256, 0, stream>>>(sid, S, offs, order, tileE, tileR, ntl);
  prep_kernel<<<dim3(2048), 256, 0, stream>>>(
      x, order, xg, W1, w1t, W2, w2t, Wg1, wg1t, Wg2, wg2t);

  // GEMM1: h = gelu(xg @ W1[e] + b1[e])   [sorted rows in/out]
  gemm_expert<true, false><<<dim3(H / 128, 144), 256, 0, stream>>>(
      xg, w1t, b1, hbuf, H, D, order, offs, tileE, tileR, ntl, S, (long)H * D, H);
  // GEMM2: rout = h @ W2[e] + b2[e]       [sorted in, scatter to natural rows]
  gemm_expert<false, true><<<dim3(D / 128, 144), 256, 0, stream>>>(
      hbuf, w2t, b2, rout, D, H, order, offs, tileE, tileR, ntl, S, (long)D * H, D);
  // GEMM3: g = gelu(rout @ Wg1 + bg1)     [writes xg region (xg no longer needed)]
  gemm_dense128<true, false><<<dim3((unsigned)(NT / 128) * (D / 128)), 256, 0, stream>>>(
      rout, wg1t, bg1, xg, D, D, D / 128);
  // GEMM4: out = g @ Wg2 + bg2            [fp32 to d_out]
  gemm_dense128<false, true><<<dim3((unsigned)(NT / 128) * (D / 128)), 256, 0, stream>>>(
      xg, wg2t, bg2, d_out, D, D, D / 128);
}